// Round 3
// baseline (975.618 us; speedup 1.0000x reference)
//
#include <hip/hip_runtime.h>
#include <hip/hip_bf16.h>

#define BATCH 8
#define L 2048
#define D 1024

// ws layout: ah,al,bh,bl (B*L*D bf16 each, row-major split) | at,bt (B*D*L bf16,
// transposed) | slots. Slot (floats): e (L*L) | eT (L*L) | Pr,PcT (L*L us each
// = L*L floats) | pad
#define SLOT_F (3*L*L + 8)

typedef unsigned short us;
typedef __attribute__((ext_vector_type(8))) short bf16x8;
typedef __attribute__((ext_vector_type(4))) float f32x4;

// async global->LDS, 16B/lane; LDS dest = uniform base + lane*16
#define GLDS(dst, src) __builtin_amdgcn_global_load_lds( \
    (const __attribute__((address_space(1))) unsigned int*)(src), \
    (__attribute__((address_space(3))) unsigned int*)(dst), 16, 0, 0)

static __device__ inline us f2bf(float x) {
  union { float f; unsigned u; } v; v.f = x;
  unsigned r = v.u + 0x7fff + ((v.u >> 16) & 1);   // RNE (inputs finite)
  return (us)(r >> 16);
}
static __device__ inline float bf2f(us h) {
  union { unsigned u; float f; } v; v.u = ((unsigned)h) << 16; return v.f;
}
static __device__ inline unsigned pack2(float x, float y) {
  return (unsigned)f2bf(x) | ((unsigned)f2bf(y) << 16);
}
static __device__ inline void split2(float x, float y, unsigned &hi, unsigned &lo) {
  us hx = f2bf(x), hy = f2bf(y);
  float rx = x - bf2f(hx), ry = y - bf2f(hy);
  hi = (unsigned)hx | ((unsigned)hy << 16);
  lo = (unsigned)f2bf(rx) | ((unsigned)f2bf(ry) << 16);
}

// ---------------------------------------------------------------------------
// k_split: a,b fp32 -> row-major split bf16 (hi + residual-lo). Streaming.
// ---------------------------------------------------------------------------
__global__ __launch_bounds__(256) void k_split(const float* __restrict__ A,
                                               const float* __restrict__ Bm,
                                               us* __restrict__ ah, us* __restrict__ al,
                                               us* __restrict__ bh, us* __restrict__ bl) {
  const float* src = blockIdx.z ? Bm : A;
  us* dh = blockIdx.z ? bh : ah;
  us* dl = blockIdx.z ? bl : al;
  size_t idx = (size_t)blockIdx.x * 256 + threadIdx.x;  // float4 index
  float4 v = *((const float4*)src + idx);
  unsigned h0, l0, h1, l1;
  split2(v.x, v.y, h0, l0); split2(v.z, v.w, h1, l1);
  *((uint2*)dh + idx) = make_uint2(h0, h1);
  *((uint2*)dl + idx) = make_uint2(l0, l1);
}

// ---------------------------------------------------------------------------
// k_prep: at[b][d][i] = bf16(a[b][i][d]); bt likewise. Stride-65 LDS transpose.
// ---------------------------------------------------------------------------
__global__ __launch_bounds__(256) void k_prep(const float* __restrict__ A,
                                              const float* __restrict__ Bm,
                                              us* __restrict__ at, us* __restrict__ bt) {
  const int z = blockIdx.z, batch = z & 7;
  const float* src = (z < 8 ? A : Bm) + (size_t)batch * L * D;
  us* dst = (z < 8 ? at : bt) + (size_t)batch * D * L;
  const int i0 = blockIdx.x * 64, d0 = blockIdx.y * 64;
  __shared__ float sT[64][65];
  const int tid = threadIdx.x;
#pragma unroll
  for (int it = 0; it < 4; ++it) {
    int idx = tid + it * 256;
    int row = idx >> 4, c4 = (idx & 15) * 4;
    float4 v = *(const float4*)(src + (size_t)(i0 + row) * D + d0 + c4);
    sT[row][c4 + 0] = v.x; sT[row][c4 + 1] = v.y;
    sT[row][c4 + 2] = v.z; sT[row][c4 + 3] = v.w;
  }
  __syncthreads();
#pragma unroll
  for (int it = 0; it < 4; ++it) {
    int idx = tid + it * 256;
    int orow = idx >> 4, c4 = (idx & 15) * 4;
    uint2 o = make_uint2(pack2(sT[c4 + 0][orow], sT[c4 + 1][orow]),
                         pack2(sT[c4 + 2][orow], sT[c4 + 3][orow]));
    *(uint2*)&dst[(size_t)(d0 + orow) * L + i0 + c4] = o;
  }
}

// ---------------------------------------------------------------------------
// k_gemm_e: e = a @ b^T via split-bf16 (hh+hl+lh). Pure-bf16 glds staging,
// 128x128 tile, BK=32, 48 MFMA/iter. Epilogue writes e AND eT.
// ---------------------------------------------------------------------------
__global__ __launch_bounds__(256) void k_gemm_e(const us* __restrict__ AH,
                                                const us* __restrict__ AL,
                                                const us* __restrict__ BH,
                                                const us* __restrict__ BL,
                                                float* __restrict__ ws, int b0) {
  const int bz = blockIdx.z, batch = b0 + bz;
  const size_t boff = (size_t)batch * L * D;
  const us* ah = AH + boff; const us* al = AL + boff;
  const us* bh = BH + boff; const us* bl = BL + boff;
  float* e = ws + (size_t)bz * SLOT_F;
  float* eT = e + (size_t)L * L;
  const int i0 = blockIdx.x * 128, j0 = blockIdx.y * 128;
  __shared__ us sAh[128][32], sAl[128][32], sBh[128][32], sBl[128][32];
  const int tid = threadIdx.x;
  const int lane = tid & 63, wave = tid >> 6;
  const int wm = (wave & 1) * 64, wn = (wave >> 1) * 64;
  const int q = lane >> 4, lr = lane & 15;
  // glds: wave stages rows [wave*32, wave*32+32) of each tile; 16 rows/instr
  const size_t rowA = (size_t)(i0 + wave * 32 + (lane >> 2)) * D + (lane & 3) * 8;
  const size_t rowB = (size_t)(j0 + wave * 32 + (lane >> 2)) * D + (lane & 3) * 8;
  const size_t r16 = (size_t)16 * D;
  us* dA0 = &sAh[wave * 32][0];  us* dA1 = &sAh[wave * 32 + 16][0];
  us* dA2 = &sAl[wave * 32][0];  us* dA3 = &sAl[wave * 32 + 16][0];
  us* dB0 = &sBh[wave * 32][0];  us* dB1 = &sBh[wave * 32 + 16][0];
  us* dB2 = &sBl[wave * 32][0];  us* dB3 = &sBl[wave * 32 + 16][0];
  f32x4 acc[4][4] = {};
  for (int k0 = 0; k0 < D; k0 += 32) {
    __syncthreads();
    GLDS(dA0, ah + rowA + k0); GLDS(dA1, ah + rowA + r16 + k0);
    GLDS(dA2, al + rowA + k0); GLDS(dA3, al + rowA + r16 + k0);
    GLDS(dB0, bh + rowB + k0); GLDS(dB1, bh + rowB + r16 + k0);
    GLDS(dB2, bl + rowB + k0); GLDS(dB3, bl + rowB + r16 + k0);
    __syncthreads();
    bf16x8 fah[4], fal[4], fbh[4], fbl[4];
#pragma unroll
    for (int t = 0; t < 4; ++t) {
      fah[t] = *(const bf16x8*)&sAh[wm + t * 16 + lr][q * 8];
      fal[t] = *(const bf16x8*)&sAl[wm + t * 16 + lr][q * 8];
      fbh[t] = *(const bf16x8*)&sBh[wn + t * 16 + lr][q * 8];
      fbl[t] = *(const bf16x8*)&sBl[wn + t * 16 + lr][q * 8];
    }
#pragma unroll
    for (int mi = 0; mi < 4; ++mi)
#pragma unroll
      for (int ni = 0; ni < 4; ++ni) {
        acc[mi][ni] = __builtin_amdgcn_mfma_f32_16x16x32_bf16(fah[mi], fbh[ni], acc[mi][ni], 0, 0, 0);
        acc[mi][ni] = __builtin_amdgcn_mfma_f32_16x16x32_bf16(fah[mi], fbl[ni], acc[mi][ni], 0, 0, 0);
        acc[mi][ni] = __builtin_amdgcn_mfma_f32_16x16x32_bf16(fal[mi], fbh[ni], acc[mi][ni], 0, 0, 0);
      }
  }
  // C/D layout: col = lane&15, row = q*4 + reg
#pragma unroll
  for (int mi = 0; mi < 4; ++mi)
#pragma unroll
    for (int ni = 0; ni < 4; ++ni) {
      const int gi = i0 + wm + mi * 16 + q * 4, gj = j0 + wn + ni * 16 + lr;
#pragma unroll
      for (int r = 0; r < 4; ++r)
        e[(size_t)(gi + r) * L + gj] = acc[mi][ni][r];
      *(float4*)&eT[(size_t)gj * L + gi] =
          make_float4(acc[mi][ni][0], acc[mi][ni][1], acc[mi][ni][2], acc[mi][ni][3]);
    }
}

// ---------------------------------------------------------------------------
// k_softmax: one block per row of mat (e or eT): compute max & sum, write
// normalized bf16 P row. pSel: 0 -> Pr, 1 -> PcT.
// ---------------------------------------------------------------------------
__global__ __launch_bounds__(256) void k_softmax(float* __restrict__ ws,
                                                 int matOff, int pSel) {
  float* slot = ws + (size_t)blockIdx.y * SLOT_F;
  const int row = blockIdx.x, tid = threadIdx.x;
  const float* er = slot + matOff + (size_t)row * L;
  us* P = (us*)(slot + (size_t)2 * L * L) + (size_t)pSel * L * L + (size_t)row * L;
  float4 v0 = *(const float4*)(er + tid * 8);
  float4 v1 = *(const float4*)(er + tid * 8 + 4);
  float v[8] = {v0.x, v0.y, v0.z, v0.w, v1.x, v1.y, v1.z, v1.w};
  float m = v[0];
#pragma unroll
  for (int r = 1; r < 8; ++r) m = fmaxf(m, v[r]);
  __shared__ float red[4];
#pragma unroll
  for (int o = 32; o; o >>= 1) m = fmaxf(m, __shfl_xor(m, o));
  if ((tid & 63) == 0) red[tid >> 6] = m;
  __syncthreads();
  m = fmaxf(fmaxf(red[0], red[1]), fmaxf(red[2], red[3]));
  float p[8], s = 0.f;
#pragma unroll
  for (int r = 0; r < 8; ++r) { p[r] = __expf(v[r] - m); s += p[r]; }
  __syncthreads();
#pragma unroll
  for (int o = 32; o; o >>= 1) s += __shfl_xor(s, o);
  if ((tid & 63) == 0) red[tid >> 6] = s;
  __syncthreads();
  float inv = 1.0f / (red[0] + red[1] + red[2] + red[3]);
  uint4 o = make_uint4(pack2(p[0] * inv, p[1] * inv), pack2(p[2] * inv, p[3] * inv),
                       pack2(p[4] * inv, p[5] * inv), pack2(p[6] * inv, p[7] * inv));
  *(uint4*)&P[tid * 8] = o;
}

// ---------------------------------------------------------------------------
// k_pv: out[m][d] = sum_k P[m][k] * Wt[d][k].  Pure bf16 m97-style GEMM:
// glds staging both operands, 128x128 tile, BK=32, 16 MFMA/iter.
// ---------------------------------------------------------------------------
__global__ __launch_bounds__(256) void k_pv(const us* __restrict__ Wt,
                                            float* __restrict__ ws, int pSel,
                                            float* __restrict__ outB, int b0) {
  const int bz = blockIdx.z, batch = b0 + bz;
  float* slot = ws + (size_t)bz * SLOT_F;
  const us* P = (const us*)(slot + (size_t)2 * L * L) + (size_t)pSel * L * L;
  const us* W = Wt + (size_t)batch * D * L;
  const int m0 = blockIdx.x * 128, d0 = blockIdx.y * 128;
  __shared__ us sP[128][32], sW[128][32];
  const int tid = threadIdx.x;
  const int lane = tid & 63, wave = tid >> 6;
  const int wm = (wave & 1) * 64, wn = (wave >> 1) * 64;
  const int q = lane >> 4, lr = lane & 15;
  const size_t rowP = (size_t)(m0 + wave * 32 + (lane >> 2)) * L + (lane & 3) * 8;
  const size_t rowW = (size_t)(d0 + wave * 32 + (lane >> 2)) * L + (lane & 3) * 8;
  const size_t r16 = (size_t)16 * L;
  us* dP0 = &sP[wave * 32][0];  us* dP1 = &sP[wave * 32 + 16][0];
  us* dW0 = &sW[wave * 32][0];  us* dW1 = &sW[wave * 32 + 16][0];
  f32x4 acc[4][4] = {};
  for (int k0 = 0; k0 < L; k0 += 32) {
    __syncthreads();
    GLDS(dP0, P + rowP + k0); GLDS(dP1, P + rowP + r16 + k0);
    GLDS(dW0, W + rowW + k0); GLDS(dW1, W + rowW + r16 + k0);
    __syncthreads();
    bf16x8 fa[4], fb[4];
#pragma unroll
    for (int t = 0; t < 4; ++t) {
      fa[t] = *(const bf16x8*)&sP[wm + t * 16 + lr][q * 8];
      fb[t] = *(const bf16x8*)&sW[wn + t * 16 + lr][q * 8];
    }
#pragma unroll
    for (int mi = 0; mi < 4; ++mi)
#pragma unroll
      for (int ni = 0; ni < 4; ++ni)
        acc[mi][ni] = __builtin_amdgcn_mfma_f32_16x16x32_bf16(fa[mi], fb[ni], acc[mi][ni], 0, 0, 0);
  }
  float* o = outB + (size_t)batch * L * D;
#pragma unroll
  for (int mi = 0; mi < 4; ++mi)
#pragma unroll
    for (int ni = 0; ni < 4; ++ni)
#pragma unroll
      for (int r = 0; r < 4; ++r)
        o[(size_t)(m0 + wm + mi * 16 + q * 4 + r) * D + (d0 + wn + ni * 16 + lr)] =
            acc[mi][ni][r];
}

extern "C" void kernel_launch(void* const* d_in, const int* in_sizes, int n_in,
                              void* d_out, int out_size, void* d_ws, size_t ws_size,
                              hipStream_t stream) {
  const float* a = (const float*)d_in[0];
  const float* b = (const float*)d_in[1];
  float* out = (float*)d_out;
  const size_t N = (size_t)BATCH * L * D;
  us* ah = (us*)d_ws;
  us* al = ah + N; us* bh = al + N; us* bl = bh + N;
  us* at = bl + N; us* bt = at + N;
  float* slots = (float*)(bt + N);
  const size_t fixed = 6 * N * sizeof(us);
  const size_t slotB = (size_t)SLOT_F * sizeof(float);
  int S = 1;
  if (ws_size > fixed + slotB) S = (int)((ws_size - fixed) / slotB);
  if (S > BATCH) S = BATCH;
  if (S < 1) S = 1;

  hipLaunchKernelGGL(k_split, dim3((unsigned)(N / 4 / 256), 1, 2), dim3(256), 0, stream,
                     a, b, ah, al, bh, bl);
  hipLaunchKernelGGL(k_prep, dim3(L / 64, D / 64, 2 * BATCH), dim3(256), 0, stream,
                     a, b, at, bt);
  for (int b0 = 0; b0 < BATCH; b0 += S) {
    int nb = (BATCH - b0 < S) ? (BATCH - b0) : S;
    hipLaunchKernelGGL(k_gemm_e, dim3(16, 16, nb), dim3(256), 0, stream,
                       ah, al, bh, bl, slots, b0);
    hipLaunchKernelGGL(k_softmax, dim3(L, nb), dim3(256), 0, stream, slots, 0, 0);
    hipLaunchKernelGGL(k_softmax, dim3(L, nb), dim3(256), 0, stream, slots, L * L, 1);
    hipLaunchKernelGGL(k_pv, dim3(16, 8, nb), dim3(256), 0, stream,
                       bt, slots, 0, out, b0);
    hipLaunchKernelGGL(k_pv, dim3(16, 8, nb), dim3(256), 0, stream,
                       at, slots, 1, out + N, b0);
  }
}